// Round 24
// baseline (115.524 us; speedup 1.0000x reference)
//
#include <hip/hip_runtime.h>
#include <hip/hip_bf16.h>
#include <cstdint>

// Problem: B=2, S=2048, D=1024, H=16, DK=64. fp32 I/O, bf16 MFMA compute.
#define B_ 2
#define S_ 2048
#define D_ 1024
#define H_ 16
#define DK_ 64

// 1/sqrt(DK) * log2(e): folded into Q during the QKV GEMM epilogue.
#define LOG2E_S 0.18033688f

// split-K attention: pairs ii=10..15 are split into 2 KV chunks.
#define SPLIT_LO 10
#define NPROWS 24576   // 6 pairs * 32 bh * 2 sides * 64 rows

typedef __attribute__((ext_vector_type(8))) short bf16x8;
typedef __attribute__((ext_vector_type(4))) float f32x4;

__device__ __forceinline__ unsigned short f2bf(float f) {
  unsigned u = __float_as_uint(f);
  u = (u + 0x7FFFu + ((u >> 16) & 1u)) >> 16;
  return (unsigned short)u;
}

// HW bf16 convert (compiler emits/pairs v_cvt_pk_bf16_f32; m240: scalar cast form)
__device__ __forceinline__ unsigned short f2bf_hw(float f) {
  __hip_bfloat16 h = __float2bfloat16(f);
  return *reinterpret_cast<unsigned short*>(&h);
}

typedef __attribute__((address_space(1))) void gv_t;
typedef __attribute__((address_space(3))) void lv_t;
__device__ __forceinline__ void gl16(const void* g, void* l) {
  __builtin_amdgcn_global_load_lds((gv_t*)g, (lv_t*)l, 16, 0, 0);
}

// ---- swizzled staging (T21: linear gl16 dest + inverse-swizzled source) ----
// 8-wave: 64x64 tile = 8 chunks of 8 rows; wave w stages chunk w exactly (8 KB).
__device__ __forceinline__ void stage8w(const unsigned short* gbase, size_t ldg,
                                        unsigned short* lds, int wave, int lane) {
  const int lr = lane >> 3;
  const int col8 = (lane & 7) ^ lr;
  gl16(gbase + (size_t)(wave * 8 + lr) * ldg + col8 * 8, lds + wave * 512);
}

// swizzled fragment read from a [rows][64] tile
__device__ __forceinline__ bf16x8 rdswz(const unsigned short* lds, int row, int col) {
  return *(const bf16x8*)&lds[row * 64 + (col ^ ((row & 7) << 3))];
}

// ---------------- fp32 -> bf16 convert: grid-stride over virtual concat ----------------
__global__ void cvt_all_kernel(const float* __restrict__ x,
                               const float* __restrict__ w0, const float* __restrict__ w1,
                               const float* __restrict__ w2, const float* __restrict__ w3,
                               unsigned short* __restrict__ xo,
                               unsigned short* __restrict__ o0, unsigned short* __restrict__ o1,
                               unsigned short* __restrict__ o2, unsigned short* __restrict__ o3) {
  const int NX4 = 1 << 20;                 // x float4 count
  const int TOT = 1 << 21;                 // total float4 count
  for (int i = blockIdx.x * blockDim.x + threadIdx.x; i < TOT; i += gridDim.x * blockDim.x) {
    const float* in;
    unsigned short* out;
    int off;
    if (i < NX4) {
      in = x; out = xo; off = i;
    } else {
      int j = i - NX4;
      int mat = j >> 18;                   // 0..3
      off = j & ((1 << 18) - 1);
      in = (mat == 0) ? w0 : (mat == 1) ? w1 : (mat == 2) ? w2 : w3;
      out = (mat == 0) ? o0 : (mat == 1) ? o1 : (mat == 2) ? o2 : o3;
    }
    const float4 v = reinterpret_cast<const float4*>(in)[off];
    ushort4 o;
    o.x = f2bf(v.x); o.y = f2bf(v.y); o.z = f2bf(v.z); o.w = f2bf(v.w);
    reinterpret_cast<ushort4*>(out)[off] = o;
  }
}

// ---------------- GEMM: C = A * B^T (r14-exact, proven) ----------------
#define BM 128
#define BK 64

template <typename OutT, bool TV2, int BNv, bool SCALEQ>
__global__ __launch_bounds__(256) void gemm_bt(
    const unsigned short* __restrict__ A,
    const unsigned short* __restrict__ B0, const unsigned short* __restrict__ B1,
    const unsigned short* __restrict__ B2,
    OutT* __restrict__ C0, OutT* __restrict__ C1, OutT* __restrict__ C2,
    int M, int N, int K) {
  constexpr int NFRAG = BNv / 32;
  __shared__ unsigned short lA[BM * BK];
  __shared__ unsigned short lB[BNv * BK];
  const int tid = threadIdx.x;
  const int wave = tid >> 6, lane = tid & 63;
  const int l16 = lane & 15, lqq = lane >> 4;
  const int wr = wave >> 1, wc = wave & 1;
  const int lr = lane >> 3;
  const int col8 = ((lane & 7) ^ lr) * 8;

  const int tilesPerMat = N / BNv;
  const int bx = blockIdx.x;
  const int mat = bx / tilesPerMat;
  const int n0 = (bx % tilesPerMat) * BNv;
  const unsigned short* Bm = (mat == 0) ? B0 : (mat == 1) ? B1 : B2;
  OutT* C = (mat == 0) ? C0 : (mat == 1) ? C1 : C2;
  const int m0 = blockIdx.y * BM;

  f32x4 acc[4][NFRAG] = {};

  for (int k0 = 0; k0 < K; k0 += BK) {
    __syncthreads();
#pragma unroll
    for (int c = wave; c < 16; c += 4)
      gl16(A + (size_t)(m0 + c * 8 + lr) * K + k0 + col8, &lA[c * 512]);
#pragma unroll
    for (int c = wave; c < BNv / 8; c += 4)
      gl16(Bm + (size_t)(n0 + c * 8 + lr) * K + k0 + col8, &lB[c * 512]);
    __syncthreads();
#pragma unroll
    for (int kk = 0; kk < BK / 32; ++kk) {
      bf16x8 af[4], bfr[NFRAG];
#pragma unroll
      for (int m = 0; m < 4; ++m)
        af[m] = rdswz(lA, wr * 64 + m * 16 + l16, kk * 32 + lqq * 8);
#pragma unroll
      for (int n = 0; n < NFRAG; ++n)
        bfr[n] = rdswz(lB, wc * (BNv / 2) + n * 16 + l16, kk * 32 + lqq * 8);
      __builtin_amdgcn_s_setprio(1);
#pragma unroll
      for (int m = 0; m < 4; ++m)
#pragma unroll
        for (int n = 0; n < NFRAG; ++n)
          acc[m][n] = __builtin_amdgcn_mfma_f32_16x16x32_bf16(af[m], bfr[n], acc[m][n], 0, 0, 0);
      __builtin_amdgcn_s_setprio(0);
    }
  }

  if (TV2 && mat == 2) {
    unsigned short* Vt = (unsigned short*)C;
#pragma unroll
    for (int m = 0; m < 4; ++m)
#pragma unroll
      for (int n = 0; n < NFRAG; ++n) {
        int r0 = m0 + wr * 64 + m * 16 + lqq * 4;
        int cidx = n0 + wc * (BNv / 2) + n * 16 + l16;
        int bb = r0 >> 11, s = r0 & 2047;
        int h = cidx >> 6, dv = cidx & 63;
        ushort4 o;
        o.x = f2bf(acc[m][n][0]); o.y = f2bf(acc[m][n][1]);
        o.z = f2bf(acc[m][n][2]); o.w = f2bf(acc[m][n][3]);
        *(ushort4*)(Vt + ((size_t)((bb * H_ + h) * DK_ + dv)) * S_ + s) = o;
      }
  } else {
    const float cscale = (SCALEQ && mat == 0) ? LOG2E_S : 1.0f;
#pragma unroll
    for (int m = 0; m < 4; ++m)
#pragma unroll
      for (int n = 0; n < NFRAG; ++n)
#pragma unroll
        for (int j = 0; j < 4; ++j) {
          int r = m0 + wr * 64 + m * 16 + lqq * 4 + j;
          int cidx = n0 + wc * (BNv / 2) + n * 16 + l16;
          float v = acc[m][n][j] * cscale;
          if constexpr (sizeof(OutT) == 4) C[(size_t)r * N + cidx] = v;
          else C[(size_t)r * N + cidx] = f2bf(v);
        }
  }
}

// ---------------- flash attention (causal, split-K) ----------------
// r23 inner loop byte-preserved (stagger, defer-max, ones-MFMA denominator),
// with: (1) per-subtile P write/consume (r16-proven; sP 16 KB -> LDS 48 KB ->
// 3 blocks/CU: ALL 704 blocks co-resident, equal-lifetime company for every
// block); (2) KV-range parametrization [kt0, ktN) + has-diag flag; (3) split
// epilogue writing unnormalized partials (m, s, O) for chunked blocks.
// Mapping: id<320 -> unsplit ii=0..9; id<512 -> chunk0 of ii=10..15; else
// chunk1. bh = (u&7)*4 + ((u>>3)&3) in every band (4 bh per XCD, r14-proven).
__global__ __launch_bounds__(512) void attn_kernel(
    const unsigned short* __restrict__ Qg, const unsigned short* __restrict__ Kg,
    const unsigned short* __restrict__ Vtg, unsigned short* __restrict__ Og,
    float* __restrict__ O0p, float* __restrict__ O1p, float* __restrict__ MSp) {
  __shared__ unsigned short sK[2][64 * 64];      // 16 KB
  __shared__ unsigned short sVt[2][64 * 64];     // 16 KB
  __shared__ unsigned short sP[8][16 * 64];      // per-wave single-subtile, 16 KB
  const int tid = threadIdx.x, wave = tid >> 6, lane = tid & 63;
  const int side = wave >> 2, wq = wave & 3;
  const int l16 = lane & 15, lq = lane >> 4;
  const int id = blockIdx.x;
  int u, ii, chunk;                                  // chunk: -1 unsplit, 0, 1
  if (id < 320)      { u = id;       ii = u >> 5;            chunk = -1; }
  else if (id < 512) { u = id - 320; ii = SPLIT_LO + (u >> 5); chunk = 0; }
  else               { u = id - 512; ii = SPLIT_LO + (u >> 5); chunk = 1; }
  const int bh = (u & 7) * 4 + ((u >> 3) & 3);       // XCD-grouped (b,h)
  const int b = bh >> 4, h = bh & 15;
  const int qtA = 2 * ii, qtB = 2 * ii + 1;
  const int qt_s = side ? qtB : qtA;                 // this wave's q-tile
  const int NTf = ii + 1;                            // full 128-kv iteration count
  const int c0 = (NTf + 1) >> 1;                     // chunk0 length
  const int kt0 = (chunk == 1) ? c0 : 0;
  const int ktN = (chunk == 0) ? c0 : NTf;
  const bool hd = (chunk != 0);                      // this block's range has the diagonal
  const size_t tokbase = (size_t)b * S_ * D_ + h * DK_;
  const unsigned short* VtB = Vtg + (size_t)(b * H_ + h) * DK_ * S_;
  unsigned short* sPw = sP[wave];

  // prologue: stage K(kt0) + Vt(kt0); Q fragments straight from global
  stage8w(Kg + tokbase + (size_t)(kt0 * 128) * D_, D_, sK[0], wave, lane);
  stage8w(Kg + tokbase + (size_t)(kt0 * 128 + 64) * D_, D_, sK[1], wave, lane);
  stage8w(VtB + kt0 * 128, S_, sVt[0], wave, lane);
  stage8w(VtB + kt0 * 128 + 64, S_, sVt[1], wave, lane);
  const unsigned short* qrow = Qg + tokbase + (size_t)(qt_s * 64 + wq * 16 + l16) * D_;
  bf16x8 aq0 = *(const bf16x8*)(qrow + lq * 8);
  bf16x8 aq1 = *(const bf16x8*)(qrow + 32 + lq * 8);
  __syncthreads();

  const float THR2 = 11.5416f;                  // 8 nats in log2
  const short ONE_BF = 0x3F80;                  // bf16 1.0
  const bf16x8 vones = {ONE_BF, ONE_BF, ONE_BF, ONE_BF, ONE_BF, ONE_BF, ONE_BF, ONE_BF};
  float m_run[4] = {-1e30f, -1e30f, -1e30f, -1e30f};
  f32x4 sum_acc = {};                           // row-sum accumulator (ones-MFMA)
  f32x4 o_acc[4] = {};

#pragma unroll 1
  for (int kt = kt0; kt < ktN; ++kt) {
    const bool last = (kt == ktN - 1);
    float p[8][4];

    // QK^T per 64-wide subtile from sK (already staged + drained).
#pragma unroll
    for (int sub = 0; sub < 2; ++sub) {
      const bool skip = hd && (sub == 1) && (side == 0) && last;
      if (!skip) {
        __builtin_amdgcn_s_setprio(1);
#pragma unroll
        for (int nb = 0; nb < 4; ++nb) {
          bf16x8 bk0 = rdswz(sK[sub], nb * 16 + l16, lq * 8);
          bf16x8 bk1 = rdswz(sK[sub], nb * 16 + l16, 32 + lq * 8);
          f32x4 a = {};
          a = __builtin_amdgcn_mfma_f32_16x16x32_bf16(aq0, bk0, a, 0, 0, 0);
          a = __builtin_amdgcn_mfma_f32_16x16x32_bf16(aq1, bk1, a, 0, 0, 0);
#pragma unroll
          for (int j = 0; j < 4; ++j) p[sub * 4 + nb][j] = a[j];
        }
        __builtin_amdgcn_s_setprio(0);
      } else {
#pragma unroll
        for (int nb = 0; nb < 4; ++nb)
#pragma unroll
          for (int j = 0; j < 4; ++j) p[sub * 4 + nb][j] = -1e30f;
      }
    }

    __syncthreads();   // (A) all waves done reading sK; drains Vt(kt) staging
    if (kt + 1 < ktN) { // stage K(kt+1): flies under softmax + PV below
      stage8w(Kg + tokbase + (size_t)((kt + 1) * 128) * D_, D_, sK[0], wave, lane);
      stage8w(Kg + tokbase + (size_t)((kt + 1) * 128 + 64) * D_, D_, sK[1], wave, lane);
    }

    // causal diagonal mask — only blocks whose range contains the diagonal
    if (hd && last) {
      if (side == 0) {
#pragma unroll
        for (int nb = 0; nb < 4; ++nb)
#pragma unroll
          for (int j = 0; j < 4; ++j) {
            int kidx = nb * 16 + l16;
            int qidx = wq * 16 + lq * 4 + j;
            if (kidx > qidx) p[nb][j] = -1e30f;
          }
      } else {
#pragma unroll
        for (int nb = 0; nb < 4; ++nb)
#pragma unroll
          for (int j = 0; j < 4; ++j) {
            int kidx = nb * 16 + l16;
            int qidx = wq * 16 + lq * 4 + j;
            if (kidx > qidx) p[4 + nb][j] = -1e30f;
          }
      }
    }

    // T13 defer-max: in-lane tile max; rescale only when wave-wide check trips
    float pmax[4];
    bool ok = true;
#pragma unroll
    for (int j = 0; j < 4; ++j) {
      float r = p[0][j];
#pragma unroll
      for (int nbb = 1; nbb < 8; ++nbb) r = fmaxf(r, p[nbb][j]);
      pmax[j] = r;
      ok = ok && (r <= m_run[j] + THR2);
    }
    if (!__all((int)ok)) {
#pragma unroll
      for (int j = 0; j < 4; ++j) {
        float r = pmax[j];
#pragma unroll
        for (int d = 1; d < 16; d <<= 1) r = fmaxf(r, __shfl_xor(r, d));
        float mn = fmaxf(m_run[j], r);
        float alpha = exp2f(m_run[j] - mn);
        m_run[j] = mn;
        sum_acc[j] *= alpha;
#pragma unroll
        for (int nb = 0; nb < 4; ++nb) o_acc[nb][j] *= alpha;
      }
    }
    // e = exp2(p - m_run), in place
#pragma unroll
    for (int j = 0; j < 4; ++j)
#pragma unroll
      for (int nbb = 0; nbb < 8; ++nbb)
        p[nbb][j] = exp2f(p[nbb][j] - m_run[j]);

    // per subtile (r16-proven): write P (wave-private) then PV + ones-MFMA sum
#pragma unroll
    for (int sub = 0; sub < 2; ++sub) {
#pragma unroll
      for (int j = 0; j < 4; ++j) {
        const int rw = lq * 4 + j;
#pragma unroll
        for (int nb = 0; nb < 4; ++nb)
          sPw[rw * 64 + (((nb * 16 + l16) ^ ((rw & 7) << 3)))] = f2bf_hw(p[sub * 4 + nb][j]);
      }
      __builtin_amdgcn_s_setprio(1);
#pragma unroll
      for (int kk = 0; kk < 2; ++kk) {
        bf16x8 ap = rdswz(sPw, l16, kk * 32 + lq * 8);
        sum_acc = __builtin_amdgcn_mfma_f32_16x16x32_bf16(ap, vones, sum_acc, 0, 0, 0);
#pragma unroll
        for (int nb = 0; nb < 4; ++nb) {
          bf16x8 bv = rdswz(sVt[sub], nb * 16 + l16, kk * 32 + lq * 8);
          o_acc[nb] = __builtin_amdgcn_mfma_f32_16x16x32_bf16(ap, bv, o_acc[nb], 0, 0, 0);
        }
      }
      __builtin_amdgcn_s_setprio(0);
    }

    __syncthreads();   // (B) all waves done reading sVt; drains K(kt+1) staging
    if (kt + 1 < ktN) { // stage Vt(kt+1): flies under the NEXT iteration's QK^T
      stage8w(VtB + (kt + 1) * 128, S_, sVt[0], wave, lane);
      stage8w(VtB + (kt + 1) * 128 + 64, S_, sVt[1], wave, lane);
    }
  }

  // epilogue
  if (chunk < 0) {
    // unsplit: normalize + store bf16 (sum_acc cols identical -> row-sums)
#pragma unroll
    for (int j = 0; j < 4; ++j) {
      float inv = 1.f / sum_acc[j];
#pragma unroll
      for (int nb = 0; nb < 4; ++nb) {
        int r = qt_s * 64 + wq * 16 + lq * 4 + j;
        Og[tokbase + (size_t)r * D_ + nb * 16 + l16] = f2bf(o_acc[nb][j] * inv);
      }
    }
  } else {
    // split: write unnormalized partials (m, s, O) for the combine pass
    float* Op = chunk ? O1p : O0p;
    const int prb = ((((ii - SPLIT_LO) * 32 + bh) * 2 + side) * 64) + wq * 16 + lq * 4;
#pragma unroll
    for (int j = 0; j < 4; ++j) {
#pragma unroll
      for (int nb = 0; nb < 4; ++nb)
        Op[(size_t)(prb + j) * 64 + nb * 16 + l16] = o_acc[nb][j];
      if (l16 == 0) {
        MSp[((size_t)chunk * NPROWS + prb + j) * 2] = m_run[j];
        MSp[((size_t)chunk * NPROWS + prb + j) * 2 + 1] = sum_acc[j];
      }
    }
  }
}

// ---------------- split-K combine: O = (O0*a0 + O1*a1) / (s0*a0 + s1*a1) ----------------
__global__ __launch_bounds__(256) void combine_kernel(
    const float* __restrict__ O0, const float* __restrict__ O1,
    const float* __restrict__ MS, unsigned short* __restrict__ Og) {
  int t = blockIdx.x * 256 + threadIdx.x;   // NPROWS*4 threads
  int r = t >> 2, d0 = (t & 3) * 16;
  int pi = r >> 12;                          // pair index 0..5 (ii = 10+pi)
  int rem = r & 4095;
  int bh = rem >> 7, side = (rem >> 6) & 1, row = rem & 63;
  int qt = 2 * (SPLIT_LO + pi) + side;
  int b = bh >> 4, h = bh & 15;
  float m0 = MS[(size_t)r * 2],            s0 = MS[(size_t)r * 2 + 1];
  float m1 = MS[(size_t)(NPROWS + r) * 2], s1 = MS[(size_t)(NPROWS + r) * 2 + 1];
  float m = fmaxf(m0, m1);
  float a0 = exp2f(m0 - m), a1 = exp2f(m1 - m);
  float inv = 1.f / (s0 * a0 + s1 * a1);
  size_t obase = (size_t)b * S_ * D_ + h * DK_ + (size_t)(qt * 64 + row) * D_ + d0;
  size_t pbase = (size_t)r * 64 + d0;
#pragma unroll
  for (int d = 0; d < 16; ++d) {
    float o = (O0[pbase + d] * a0 + O1[pbase + d] * a1) * inv;
    Og[obase + d] = f2bf(o);
  }
}

// ---------------- launch ----------------
extern "C" void kernel_launch(void* const* d_in, const int* in_sizes, int n_in,
                              void* d_out, int out_size, void* d_ws, size_t ws_size,
                              hipStream_t stream) {
  const float* x = (const float*)d_in[0];
  const float* wq = (const float*)d_in[1];
  const float* wk = (const float*)d_in[2];
  const float* wv = (const float*)d_in[3];
  const float* wo = (const float*)d_in[4];
  float* out = (float*)d_out;

  char* ws = (char*)d_ws;
  const size_t MB = 1024 * 1024;
  unsigned short* xb  = (unsigned short*)(ws + 0);        // 8MB (dead after QKV GEMM)
  unsigned short* wqb = (unsigned short*)(ws + 8 * MB);   // dead after QKV GEMM
  unsigned short* wkb = (unsigned short*)(ws + 10 * MB);
  unsigned short* wvb = (unsigned short*)(ws + 12 * MB);
  unsigned short* wob = (unsigned short*)(ws + 14 * MB);  // LIVE until out-proj
  unsigned short* Qb  = (unsigned short*)(ws + 16 * MB);  // 8MB, pre-scaled by LOG2E_S
  unsigned short* Kb  = (unsigned short*)(ws + 24 * MB);  // 8MB
  unsigned short* Vtb = (unsigned short*)(ws + 32 * MB);  // 8MB, V^T written by GEMM
  unsigned short* AOb = (unsigned short*)(ws + 40 * MB);  // 8MB
  // split-K partials overlay the dead regions:
  float* O0p = (float*)(ws + 0);                          // 6MB in xb
  float* MSp = (float*)(ws + 6 * MB);                     // 384KB in xb tail
  float* O1p = (float*)(ws + 8 * MB);                     // 6MB in wqb..wvb

  const int M = B_ * S_;
  const int N = D_, K = D_;

  // grid-stride convert of x + all four weights (dense 2048-block launch)
  cvt_all_kernel<<<dim3(2048), 256, 0, stream>>>(
      x, wq, wk, wv, wo, xb, wqb, wkb, wvb, wob);

  // fused QKV projection; Q (mat 0) pre-scaled; V (mat 2) written transposed
  gemm_bt<unsigned short, true, 128, true><<<dim3(3 * (N / 128), M / BM), 256, 0, stream>>>(
      xb, wqb, wkb, wvb, Qb, Kb, Vtb, M, N, K);

  // causal flash attention (split-K: 704 blocks, all co-resident at 48KB LDS)
  attn_kernel<<<dim3(704), 512, 0, stream>>>(Qb, Kb, Vtb, AOb, O0p, O1p, MSp);

  // combine split partials into AOb
  combine_kernel<<<dim3(NPROWS * 4 / 256), 256, 0, stream>>>(O0p, O1p, MSp, AOb);

  // output projection -> fp32 d_out (BN=64: 512 blocks = 2/CU)
  gemm_bt<float, false, 64, false><<<dim3(N / 64, M / BM), 256, 0, stream>>>(
      AOb, wob, wob, wob, out, out, out, M, N, K);
}

// Round 25
// 105.082 us; speedup vs baseline: 1.0994x; 1.0994x over previous
//
#include <hip/hip_runtime.h>
#include <hip/hip_bf16.h>
#include <cstdint>

// Problem: B=2, S=2048, D=1024, H=16, DK=64. fp32 I/O, bf16 MFMA compute.
#define B_ 2
#define S_ 2048
#define D_ 1024
#define H_ 16
#define DK_ 64

// 1/sqrt(DK) * log2(e): folded into Q during the QKV GEMM epilogue.
#define LOG2E_S 0.18033688f

typedef __attribute__((ext_vector_type(8))) short bf16x8;
typedef __attribute__((ext_vector_type(4))) float f32x4;

__device__ __forceinline__ unsigned short f2bf(float f) {
  unsigned u = __float_as_uint(f);
  u = (u + 0x7FFFu + ((u >> 16) & 1u)) >> 16;
  return (unsigned short)u;
}

// HW bf16 convert (compiler emits/pairs v_cvt_pk_bf16_f32; m240: scalar cast form)
__device__ __forceinline__ unsigned short f2bf_hw(float f) {
  __hip_bfloat16 h = __float2bfloat16(f);
  return *reinterpret_cast<unsigned short*>(&h);
}

typedef __attribute__((address_space(1))) void gv_t;
typedef __attribute__((address_space(3))) void lv_t;
__device__ __forceinline__ void gl16(const void* g, void* l) {
  __builtin_amdgcn_global_load_lds((gv_t*)g, (lv_t*)l, 16, 0, 0);
}

// ---- swizzled staging (T21: linear gl16 dest + inverse-swizzled source) ----
// 8-wave: 64x64 tile = 8 chunks of 8 rows; wave w stages chunk w exactly (8 KB).
__device__ __forceinline__ void stage8w(const unsigned short* gbase, size_t ldg,
                                        unsigned short* lds, int wave, int lane) {
  const int lr = lane >> 3;
  const int col8 = (lane & 7) ^ lr;
  gl16(gbase + (size_t)(wave * 8 + lr) * ldg + col8 * 8, lds + wave * 512);
}

// swizzled fragment read from a [rows][64] tile
__device__ __forceinline__ bf16x8 rdswz(const unsigned short* lds, int row, int col) {
  return *(const bf16x8*)&lds[row * 64 + (col ^ ((row & 7) << 3))];
}

// ---------------- fp32 -> bf16 convert: grid-stride over virtual concat ----------------
// Layout (float4 units): x = 2^20, then wq/wk/wv/wo = 2^18 each (total 2^21).
__global__ void cvt_all_kernel(const float* __restrict__ x,
                               const float* __restrict__ w0, const float* __restrict__ w1,
                               const float* __restrict__ w2, const float* __restrict__ w3,
                               unsigned short* __restrict__ xo,
                               unsigned short* __restrict__ o0, unsigned short* __restrict__ o1,
                               unsigned short* __restrict__ o2, unsigned short* __restrict__ o3) {
  const int NX4 = 1 << 20;                 // x float4 count
  const int TOT = 1 << 21;                 // total float4 count
  for (int i = blockIdx.x * blockDim.x + threadIdx.x; i < TOT; i += gridDim.x * blockDim.x) {
    const float* in;
    unsigned short* out;
    int off;
    if (i < NX4) {
      in = x; out = xo; off = i;
    } else {
      int j = i - NX4;
      int mat = j >> 18;                   // 0..3
      off = j & ((1 << 18) - 1);
      in = (mat == 0) ? w0 : (mat == 1) ? w1 : (mat == 2) ? w2 : w3;
      out = (mat == 0) ? o0 : (mat == 1) ? o1 : (mat == 2) ? o2 : o3;
    }
    const float4 v = reinterpret_cast<const float4*>(in)[off];
    ushort4 o;
    o.x = f2bf(v.x); o.y = f2bf(v.y); o.z = f2bf(v.z); o.w = f2bf(v.w);
    reinterpret_cast<ushort4*>(out)[off] = o;
  }
}

// ---------------- GEMM: C = A * B^T (r14-exact, proven) ----------------
#define BM 128
#define BK 64

template <typename OutT, bool TV2, int BNv, bool SCALEQ>
__global__ __launch_bounds__(256) void gemm_bt(
    const unsigned short* __restrict__ A,
    const unsigned short* __restrict__ B0, const unsigned short* __restrict__ B1,
    const unsigned short* __restrict__ B2,
    OutT* __restrict__ C0, OutT* __restrict__ C1, OutT* __restrict__ C2,
    int M, int N, int K) {
  constexpr int NFRAG = BNv / 32;          // col fragments per wave
  __shared__ unsigned short lA[BM * BK];
  __shared__ unsigned short lB[BNv * BK];
  const int tid = threadIdx.x;
  const int wave = tid >> 6, lane = tid & 63;
  const int l16 = lane & 15, lqq = lane >> 4;
  const int wr = wave >> 1, wc = wave & 1;
  const int lr = lane >> 3;
  const int col8 = ((lane & 7) ^ lr) * 8;

  const int tilesPerMat = N / BNv;
  const int bx = blockIdx.x;
  const int mat = bx / tilesPerMat;
  const int n0 = (bx % tilesPerMat) * BNv;
  const unsigned short* Bm = (mat == 0) ? B0 : (mat == 1) ? B1 : B2;
  OutT* C = (mat == 0) ? C0 : (mat == 1) ? C1 : C2;
  const int m0 = blockIdx.y * BM;

  f32x4 acc[4][NFRAG] = {};

  for (int k0 = 0; k0 < K; k0 += BK) {
    __syncthreads();
#pragma unroll
    for (int c = wave; c < 16; c += 4)                 // A: 128 rows = 16 chunks
      gl16(A + (size_t)(m0 + c * 8 + lr) * K + k0 + col8, &lA[c * 512]);
#pragma unroll
    for (int c = wave; c < BNv / 8; c += 4)            // B: BNv rows
      gl16(Bm + (size_t)(n0 + c * 8 + lr) * K + k0 + col8, &lB[c * 512]);
    __syncthreads();
#pragma unroll
    for (int kk = 0; kk < BK / 32; ++kk) {
      bf16x8 af[4], bfr[NFRAG];
#pragma unroll
      for (int m = 0; m < 4; ++m)
        af[m] = rdswz(lA, wr * 64 + m * 16 + l16, kk * 32 + lqq * 8);
#pragma unroll
      for (int n = 0; n < NFRAG; ++n)
        bfr[n] = rdswz(lB, wc * (BNv / 2) + n * 16 + l16, kk * 32 + lqq * 8);
      __builtin_amdgcn_s_setprio(1);
#pragma unroll
      for (int m = 0; m < 4; ++m)
#pragma unroll
        for (int n = 0; n < NFRAG; ++n)
          acc[m][n] = __builtin_amdgcn_mfma_f32_16x16x32_bf16(af[m], bfr[n], acc[m][n], 0, 0, 0);
      __builtin_amdgcn_s_setprio(0);
    }
  }

  if (TV2 && mat == 2) {
    unsigned short* Vt = (unsigned short*)C;
#pragma unroll
    for (int m = 0; m < 4; ++m)
#pragma unroll
      for (int n = 0; n < NFRAG; ++n) {
        int r0 = m0 + wr * 64 + m * 16 + lqq * 4;
        int cidx = n0 + wc * (BNv / 2) + n * 16 + l16;
        int bb = r0 >> 11, s = r0 & 2047;
        int h = cidx >> 6, dv = cidx & 63;
        ushort4 o;
        o.x = f2bf(acc[m][n][0]); o.y = f2bf(acc[m][n][1]);
        o.z = f2bf(acc[m][n][2]); o.w = f2bf(acc[m][n][3]);
        *(ushort4*)(Vt + ((size_t)((bb * H_ + h) * DK_ + dv)) * S_ + s) = o;
      }
  } else {
    const float cscale = (SCALEQ && mat == 0) ? LOG2E_S : 1.0f;
#pragma unroll
    for (int m = 0; m < 4; ++m)
#pragma unroll
      for (int n = 0; n < NFRAG; ++n)
#pragma unroll
        for (int j = 0; j < 4; ++j) {
          int r = m0 + wr * 64 + m * 16 + lqq * 4 + j;
          int cidx = n0 + wc * (BNv / 2) + n * 16 + l16;
          float v = acc[m][n][j] * cscale;
          if constexpr (sizeof(OutT) == 4) C[(size_t)r * N + cidx] = v;
          else C[(size_t)r * N + cidx] = f2bf(v);
        }
  }
}

// ---------------- flash attention (causal) — r23 CHAMPION (proven 46.5 us) ----------------
// 128-kv iterations + staggered K/Vt staging + Q direct from global:
//   QK(all subs) -> barrier A -> stage K(kt+1) -> mask/softmax/P-write/PV
//   -> barrier B -> stage Vt(kt+1).
__global__ __launch_bounds__(512) void attn_kernel(
    const unsigned short* __restrict__ Qg, const unsigned short* __restrict__ Kg,
    const unsigned short* __restrict__ Vtg, unsigned short* __restrict__ Og) {
  __shared__ unsigned short sK[2][64 * 64];      // 16 KB
  __shared__ unsigned short sVt[2][64 * 64];     // 16 KB
  __shared__ unsigned short sP[8][2][16 * 64];   // per-wave, two width-64 P tiles, 32 KB
  const int tid = threadIdx.x, wave = tid >> 6, lane = tid & 63;
  const int side = wave >> 2, wq = wave & 3;
  const int l16 = lane & 15, lq = lane >> 4;
  const int id = blockIdx.x;
  const int bh = (id & 7) * 4 + ((id >> 3) & 3);     // XCD-grouped (b,h); same for id+256
  const int g = (id >> 5) & 7;
  const int i = (id < 256) ? (15 - g) : g;           // heavy + light per CU, NT sum 17
  const int b = bh >> 4, h = bh & 15;
  const int qtA = 2 * i, qtB = 2 * i + 1;
  const int qt_s = side ? qtB : qtA;                 // this wave's q-tile
  const int NT = i + 1;                              // 128-kv iterations
  const size_t tokbase = (size_t)b * S_ * D_ + h * DK_;
  const unsigned short* VtB = Vtg + (size_t)(b * H_ + h) * DK_ * S_;
  unsigned short (*sPw)[16 * 64] = sP[wave];

  // prologue: stage K(0) + Vt(0); Q fragments straight from global (L2-hot)
  stage8w(Kg + tokbase, D_, sK[0], wave, lane);
  stage8w(Kg + tokbase + (size_t)64 * D_, D_, sK[1], wave, lane);
  stage8w(VtB, S_, sVt[0], wave, lane);
  stage8w(VtB + 64, S_, sVt[1], wave, lane);
  const unsigned short* qrow = Qg + tokbase + (size_t)(qt_s * 64 + wq * 16 + l16) * D_;
  bf16x8 aq0 = *(const bf16x8*)(qrow + lq * 8);
  bf16x8 aq1 = *(const bf16x8*)(qrow + 32 + lq * 8);
  __syncthreads();

  const float THR2 = 11.5416f;                  // 8 nats in log2
  const short ONE_BF = 0x3F80;                  // bf16 1.0
  const bf16x8 vones = {ONE_BF, ONE_BF, ONE_BF, ONE_BF, ONE_BF, ONE_BF, ONE_BF, ONE_BF};
  float m_run[4] = {-1e30f, -1e30f, -1e30f, -1e30f};
  f32x4 sum_acc = {};                           // row-sum accumulator (ones-MFMA)
  f32x4 o_acc[4] = {};

#pragma unroll 1
  for (int kt = 0; kt < NT; ++kt) {
    const bool last = (kt == NT - 1);
    float p[8][4];

    // QK^T per 64-wide subtile from sK (already staged + drained).
    // Q is pre-scaled by LOG2E_S, so p is directly in log2 units.
#pragma unroll
    for (int sub = 0; sub < 2; ++sub) {
      const bool skip = (sub == 1) && (side == 0) && last;
      if (!skip) {
        __builtin_amdgcn_s_setprio(1);
#pragma unroll
        for (int nb = 0; nb < 4; ++nb) {
          bf16x8 bk0 = rdswz(sK[sub], nb * 16 + l16, lq * 8);
          bf16x8 bk1 = rdswz(sK[sub], nb * 16 + l16, 32 + lq * 8);
          f32x4 a = {};
          a = __builtin_amdgcn_mfma_f32_16x16x32_bf16(aq0, bk0, a, 0, 0, 0);
          a = __builtin_amdgcn_mfma_f32_16x16x32_bf16(aq1, bk1, a, 0, 0, 0);
#pragma unroll
          for (int j = 0; j < 4; ++j) p[sub * 4 + nb][j] = a[j];
        }
        __builtin_amdgcn_s_setprio(0);
      } else {
#pragma unroll
        for (int nb = 0; nb < 4; ++nb)
#pragma unroll
          for (int j = 0; j < 4; ++j) p[sub * 4 + nb][j] = -1e30f;
      }
    }

    __syncthreads();   // (A) all waves done reading sK; drains Vt(kt) staging
    if (kt + 1 < NT) { // stage K(kt+1): flies under softmax + PV below
      stage8w(Kg + tokbase + (size_t)((kt + 1) * 128) * D_, D_, sK[0], wave, lane);
      stage8w(Kg + tokbase + (size_t)((kt + 1) * 128 + 64) * D_, D_, sK[1], wave, lane);
    }

    // causal diagonal mask — STATIC indices per side (rule #20)
    if (last) {
      if (side == 0) {
#pragma unroll
        for (int nb = 0; nb < 4; ++nb)
#pragma unroll
          for (int j = 0; j < 4; ++j) {
            int kidx = nb * 16 + l16;
            int qidx = wq * 16 + lq * 4 + j;
            if (kidx > qidx) p[nb][j] = -1e30f;
          }
      } else {
#pragma unroll
        for (int nb = 0; nb < 4; ++nb)
#pragma unroll
          for (int j = 0; j < 4; ++j) {
            int kidx = nb * 16 + l16;
            int qidx = wq * 16 + lq * 4 + j;
            if (kidx > qidx) p[4 + nb][j] = -1e30f;
          }
      }
    }

    // T13 defer-max: in-lane tile max; rescale only when wave-wide check trips
    float pmax[4];
    bool ok = true;
#pragma unroll
    for (int j = 0; j < 4; ++j) {
      float r = p[0][j];
#pragma unroll
      for (int nbb = 1; nbb < 8; ++nbb) r = fmaxf(r, p[nbb][j]);
      pmax[j] = r;
      ok = ok && (r <= m_run[j] + THR2);
    }
    if (!__all((int)ok)) {
#pragma unroll
      for (int j = 0; j < 4; ++j) {
        float r = pmax[j];
#pragma unroll
        for (int d = 1; d < 16; d <<= 1) r = fmaxf(r, __shfl_xor(r, d));
        float mn = fmaxf(m_run[j], r);
        float alpha = exp2f(m_run[j] - mn);
        m_run[j] = mn;
        sum_acc[j] *= alpha;
#pragma unroll
        for (int nb = 0; nb < 4; ++nb) o_acc[nb][j] *= alpha;
      }
    }
    // P = exp2(p - m_run) -> LDS via HW bf16 convert (sum handled by ones-MFMA)
#pragma unroll
    for (int j = 0; j < 4; ++j) {
      const int rw = lq * 4 + j;
#pragma unroll
      for (int nbb = 0; nbb < 8; ++nbb) {
        float e = exp2f(p[nbb][j] - m_run[j]);
        sPw[nbb >> 2][rw * 64 + (((nbb & 3) * 16 + l16) ^ ((rw & 7) << 3))] = f2bf_hw(e);
      }
    }

    // PV over both subtiles + denominator via ones-MFMA (reuses ap fragments)
    __builtin_amdgcn_s_setprio(1);
#pragma unroll
    for (int sub = 0; sub < 2; ++sub)
#pragma unroll
      for (int kk = 0; kk < 2; ++kk) {
        bf16x8 ap = rdswz(sPw[sub], l16, kk * 32 + lq * 8);
        sum_acc = __builtin_amdgcn_mfma_f32_16x16x32_bf16(ap, vones, sum_acc, 0, 0, 0);
#pragma unroll
        for (int nb = 0; nb < 4; ++nb) {
          bf16x8 bv = rdswz(sVt[sub], nb * 16 + l16, kk * 32 + lq * 8);
          o_acc[nb] = __builtin_amdgcn_mfma_f32_16x16x32_bf16(ap, bv, o_acc[nb], 0, 0, 0);
        }
      }
    __builtin_amdgcn_s_setprio(0);

    __syncthreads();   // (B) all waves done reading sVt; drains K(kt+1) staging
    if (kt + 1 < NT) { // stage Vt(kt+1): flies under the NEXT iteration's QK^T
      stage8w(VtB + (kt + 1) * 128, S_, sVt[0], wave, lane);
      stage8w(VtB + (kt + 1) * 128 + 64, S_, sVt[1], wave, lane);
    }
  }

  // epilogue: every lane already holds its row-sums in sum_acc (cols identical)
#pragma unroll
  for (int j = 0; j < 4; ++j) {
    float inv = 1.f / sum_acc[j];
#pragma unroll
    for (int nb = 0; nb < 4; ++nb) {
      int r = qt_s * 64 + wq * 16 + lq * 4 + j;
      Og[tokbase + (size_t)r * D_ + nb * 16 + l16] = f2bf(o_acc[nb][j] * inv);
    }
  }
}

// ---------------- launch ----------------
extern "C" void kernel_launch(void* const* d_in, const int* in_sizes, int n_in,
                              void* d_out, int out_size, void* d_ws, size_t ws_size,
                              hipStream_t stream) {
  const float* x = (const float*)d_in[0];
  const float* wq = (const float*)d_in[1];
  const float* wk = (const float*)d_in[2];
  const float* wv = (const float*)d_in[3];
  const float* wo = (const float*)d_in[4];
  float* out = (float*)d_out;

  char* ws = (char*)d_ws;
  const size_t MB = 1024 * 1024;
  unsigned short* xb  = (unsigned short*)(ws + 0);        // 8MB
  unsigned short* wqb = (unsigned short*)(ws + 8 * MB);
  unsigned short* wkb = (unsigned short*)(ws + 10 * MB);
  unsigned short* wvb = (unsigned short*)(ws + 12 * MB);
  unsigned short* wob = (unsigned short*)(ws + 14 * MB);
  unsigned short* Qb  = (unsigned short*)(ws + 16 * MB);  // 8MB, pre-scaled by LOG2E_S
  unsigned short* Kb  = (unsigned short*)(ws + 24 * MB);  // 8MB
  unsigned short* Vtb = (unsigned short*)(ws + 32 * MB);  // 8MB, V^T written by GEMM
  unsigned short* AOb = (unsigned short*)(ws + 40 * MB);  // 8MB

  const int M = B_ * S_;
  const int N = D_, K = D_;

  // grid-stride convert of x + all four weights (dense 2048-block launch)
  cvt_all_kernel<<<dim3(2048), 256, 0, stream>>>(
      x, wq, wk, wv, wo, xb, wqb, wkb, wvb, wob);

  // fused QKV projection; Q (mat 0) pre-scaled; V (mat 2) written transposed
  gemm_bt<unsigned short, true, 128, true><<<dim3(3 * (N / 128), M / BM), 256, 0, stream>>>(
      xb, wqb, wkb, wvb, Qb, Kb, Vtb, M, N, K);

  // causal flash attention (r23 champion: 128-kv + stagger + Q-direct)
  attn_kernel<<<dim3(512), 512, 0, stream>>>(Qb, Kb, Vtb, AOb);

  // output projection -> fp32 d_out (BN=64: 512 blocks = 2/CU)
  gemm_bt<float, false, 64, false><<<dim3(N / 64, M / BM), 256, 0, stream>>>(
      AOb, wob, wob, wob, out, out, out, M, N, K);
}